// Round 3
// baseline (523.752 us; speedup 1.0000x reference)
//
#include <hip/hip_runtime.h>
#include <cstdint>
#include <cstddef>

#define EPI_QKV  0
#define EPI_F32  2
#define EPI_GELU 3
#define EPI_PART 4

typedef __attribute__((ext_vector_type(8))) short bfrag8;   // 8 bf16 (4 VGPRs)
typedef __attribute__((ext_vector_type(4))) float facc4;    // 4 fp32 acc

struct PtrQuad { unsigned short* p[4]; };

__device__ __forceinline__ unsigned short f2b(float x) {
  unsigned int u = __builtin_bit_cast(unsigned int, x);
  u += 0x7FFFu + ((u >> 16) & 1u);   // RNE
  return (unsigned short)(u >> 16);
}
__device__ __forceinline__ float b2f(unsigned short u) {
  unsigned int x = ((unsigned int)u) << 16;
  return __builtin_bit_cast(float, x);
}

__device__ __forceinline__ void gl2lds16(const unsigned short* g, unsigned short* l) {
  __builtin_amdgcn_global_load_lds(
      (const __attribute__((address_space(1))) unsigned int*)g,
      (__attribute__((address_space(3))) unsigned int*)l, 16, 0, 0);
}

// ---------------- elementwise fp32 -> bf16 ----------------
__global__ __launch_bounds__(256)
void cvt_bf16_kernel(const float* __restrict__ in, unsigned short* __restrict__ out, int n4) {
  const int i = blockIdx.x * 256 + threadIdx.x;
  if (i < n4) {
    const float4 v = ((const float4*)in)[i];
    ushort4 u;
    u.x = f2b(v.x); u.y = f2b(v.y); u.z = f2b(v.z); u.w = f2b(v.w);
    ((ushort4*)out)[i] = u;
  }
}

// ---------------- transpose + convert: in (K x N) fp32 -> out (N x K) bf16 ----------------
__global__ __launch_bounds__(256)
void transpose_cvt(const float* __restrict__ in, unsigned short* __restrict__ out,
                   int K, int N) {
  __shared__ float tile[32][33];
  const int n0 = blockIdx.x * 32;
  const int k0 = blockIdx.y * 32;
  const int tx = threadIdx.x & 31, ty = threadIdx.x >> 5;  // ty 0..7
#pragma unroll
  for (int i = 0; i < 32; i += 8)
    tile[ty + i][tx] = in[(size_t)(k0 + ty + i) * N + n0 + tx];
  __syncthreads();
#pragma unroll
  for (int i = 0; i < 32; i += 8)
    out[(size_t)(n0 + ty + i) * K + k0 + tx] = f2b(tile[tx][ty + i]);
}

// ---------------- GEMM: C = A(MxK') @ Bt(NxK')^T slice, bf16 MFMA, fused epilogues ------
// 128x128 tile, BK=32, 4 waves (2x2), 4x4 16x16x32 MFMA per wave. m97 structure.
// K = k-length of this z-slice (k offset = blockIdx.z*K); ldk = full row stride of A/Bt.
template<int EPI>
__global__ __launch_bounds__(256, 2)
void gemm_bt(const unsigned short* __restrict__ A,
             const unsigned short* __restrict__ Bt,
             const float* __restrict__ bias,
             const float* __restrict__ bias2,
             const float* __restrict__ bias3,
             void* __restrict__ out, PtrQuad pq,
             int M, int N, int K, int ldk) {
  __shared__ unsigned short sA[128 * 32];
  __shared__ unsigned short sB[128 * 32];
  const int tid  = threadIdx.x;
  const int lane = tid & 63;
  const int wave = tid >> 6;
  const int l15  = lane & 15, l4 = lane >> 4;
  const int wr = wave >> 1, wc = wave & 1;
  const long row0 = (long)blockIdx.y * 128;
  const long col0 = (long)blockIdx.x * 128;
  const long k0   = (long)blockIdx.z * K;

  facc4 acc[4][4];
#pragma unroll
  for (int i = 0; i < 4; i++)
#pragma unroll
    for (int j = 0; j < 4; j++) acc[i][j] = (facc4)0.f;

  const int srow = tid >> 2;
  const int scol = (tid & 3) * 8;
  const unsigned short* Ap0 = A  + (row0 + srow) * (long)ldk + k0 + scol;
  const unsigned short* Ap1 = Ap0 + 64 * (long)ldk;
  const unsigned short* Bp0 = Bt + (col0 + srow) * (long)ldk + k0 + scol;
  const unsigned short* Bp1 = Bp0 + 64 * (long)ldk;
  const int wbase = (tid & ~63) * 8;
  unsigned short* sA0 = &sA[wbase];
  unsigned short* sA1 = &sA[2048 + wbase];
  unsigned short* sB0 = &sB[wbase];
  unsigned short* sB1 = &sB[2048 + wbase];

  const int aoff = (wr * 64 + l15) * 32 + l4 * 8;
  const int boff = (wc * 64 + l15) * 32 + l4 * 8;

  for (int kt = 0; kt < K; kt += 32) {
    gl2lds16(Ap0 + kt, sA0);
    gl2lds16(Ap1 + kt, sA1);
    gl2lds16(Bp0 + kt, sB0);
    gl2lds16(Bp1 + kt, sB1);
    __syncthreads();
    bfrag8 af[4], bf[4];
#pragma unroll
    for (int i = 0; i < 4; i++) af[i] = *(const bfrag8*)&sA[aoff + i * 512];
#pragma unroll
    for (int j = 0; j < 4; j++) bf[j] = *(const bfrag8*)&sB[boff + j * 512];
#pragma unroll
    for (int i = 0; i < 4; i++)
#pragma unroll
      for (int j = 0; j < 4; j++)
        acc[i][j] = __builtin_amdgcn_mfma_f32_16x16x32_bf16(af[i], bf[j], acc[i][j], 0, 0, 0);
    __syncthreads();
  }

#pragma unroll
  for (int i = 0; i < 4; i++) {
    const long m0 = row0 + wr * 64 + i * 16 + l4 * 4;
#pragma unroll
    for (int j = 0; j < 4; j++) {
      const long c = col0 + wc * 64 + j * 16 + l15;
      if constexpr (EPI == EPI_QKV) {
        const long which = c >> 10;
        const long cl = c & 1023;
        unsigned short* oq = (unsigned short*)out;
        if (which == 0) {
          const float bj = bias[cl];
#pragma unroll
          for (int r = 0; r < 4; r++)
            oq[(m0 + r) * 1024 + cl] = f2b((acc[i][j][r] + bj) * 0.03125f);
        } else if (which == 1) {
          const float bj = bias2[cl];
#pragma unroll
          for (int r = 0; r < 4; r++)
            (oq + 4194304)[(m0 + r) * 1024 + cl] = f2b(acc[i][j][r] + bj);
        } else {
          const float bj = bias3[cl];
          const long cc = cl >> 6, d = cl & 63;
#pragma unroll
          for (int r = 0; r < 4; r++) {
            const long m = m0 + r;
            const long nbb = m >> 10, rr = m & 1023;
            const long h = rr >> 6, rhi = rr & 63;
            const long s = rhi * 16 + cc;
            (oq + 8388608)[((nbb * 16 + h) * 64 + d) * 1024 + s] = f2b(acc[i][j][r] + bj);
          }
        }
      } else if constexpr (EPI == EPI_F32) {
        const float bj = bias[c];
        float* of = (float*)out;
#pragma unroll
        for (int r = 0; r < 4; r++) of[(m0 + r) * (long)N + c] = acc[i][j][r] + bj;
      } else if constexpr (EPI == EPI_PART) {
        unsigned short* ob = pq.p[blockIdx.z];
#pragma unroll
        for (int r = 0; r < 4; r++) ob[(m0 + r) * (long)N + c] = f2b(acc[i][j][r]);
      } else {  // EPI_GELU -> bf16
        const float bj = bias[c];
        unsigned short* ob = (unsigned short*)out;
#pragma unroll
        for (int r = 0; r < 4; r++) {
          const float t = acc[i][j][r] + bj;
          ob[(m0 + r) * (long)N + c] = f2b(0.5f * t * (1.f + erff(t * 0.70710678f)));
        }
      }
    }
  }
}

// ---------------- fused attention v3 (softmax over HEADS at each (t,s)) ----------------
// grid (64 t-tiles, 4 batches, 4 s-splits); 4 waves x 4 heads; t-tile 16; s-chunks of 32.
// Qb/Kb per-head (s,d) (Q pre-scaled 1/32); Vt per-head (d,s). bf16 partial O out.
__global__ __launch_bounds__(256, 4)
void attn_kernel(const unsigned short* __restrict__ Qb,
                 const unsigned short* __restrict__ Kb,
                 const unsigned short* __restrict__ Vt,
                 unsigned short* __restrict__ P0, unsigned short* __restrict__ P1,
                 unsigned short* __restrict__ P2, unsigned short* __restrict__ P3) {
  const int tile = blockIdx.x;
  const int nb = blockIdx.y;
  const int sp = blockIdx.z;
  const int tid = threadIdx.x, lane = tid & 63;
  const int w = __builtin_amdgcn_readfirstlane(tid >> 6);   // wave id in SGPR
  const int l15 = lane & 15, l4 = lane >> 4;
  const int t0 = tile * 16;

  __shared__ float red[2][4][576];                     // dbuf head-sum exchange, 18 KB
  __shared__ __align__(16) unsigned short abuf[4][4][16][40];  // wave-private attn, 20 KB

  const unsigned short* qB = Qb + ((size_t)(nb * 16 + w * 4) << 16);
  const unsigned short* kB = Kb + ((size_t)(nb * 16 + w * 4) << 16);
  const unsigned short* vB = Vt + ((size_t)(nb * 16 + w * 4) << 16);

  facc4 oacc[4][4];
#pragma unroll
  for (int hh = 0; hh < 4; hh++)
#pragma unroll
    for (int nt = 0; nt < 4; nt++) oacc[hh][nt] = (facc4)0.f;

  for (int it = 0; it < 8; ++it) {
    const int s0 = sp * 256 + it * 32;
    const int pb = it & 1;
    // ---- QK^T scores for 4 heads, 16t x 32s ----
    facc4 sacc[4][2];
#pragma unroll
    for (int hh = 0; hh < 4; hh++)
#pragma unroll
      for (int nt = 0; nt < 2; nt++) sacc[hh][nt] = (facc4)0.f;
#pragma unroll
    for (int hh = 0; hh < 4; hh++) {
      const unsigned short* qh = qB + (hh << 16);
      const unsigned short* kh = kB + (hh << 16);
#pragma unroll
      for (int ks = 0; ks < 2; ks++) {
        const bfrag8 qf = *(const bfrag8*)(qh + (t0 + l15) * 64 + ks * 32 + l4 * 8);
#pragma unroll
        for (int nt = 0; nt < 2; nt++) {
          const bfrag8 kf = *(const bfrag8*)(kh + (s0 + nt * 16 + l15) * 64 + ks * 32 + l4 * 8);
          sacc[hh][nt] = __builtin_amdgcn_mfma_f32_16x16x32_bf16(qf, kf, sacc[hh][nt], 0, 0, 0);
        }
      }
    }
    // ---- exp + this wave's 4-head partial sums -> red[pb][w] ----
#pragma unroll
    for (int nt = 0; nt < 2; nt++)
#pragma unroll
      for (int r = 0; r < 4; r++) {
        float s = 0.f;
#pragma unroll
        for (int hh = 0; hh < 4; hh++) {
          const float e = __expf(sacc[hh][nt][r]);
          sacc[hh][nt][r] = e;
          s += e;
        }
        red[pb][w][(l4 * 4 + r) * 36 + nt * 16 + l15] = s;
      }
    __syncthreads();
    // ---- full 16-head sum, normalize -> bf16 -> wave-private abuf ----
#pragma unroll
    for (int nt = 0; nt < 2; nt++)
#pragma unroll
      for (int r = 0; r < 4; r++) {
        const int o = (l4 * 4 + r) * 36 + nt * 16 + l15;
        const float rinv =
            1.f / (red[pb][0][o] + red[pb][1][o] + red[pb][2][o] + red[pb][3][o]);
#pragma unroll
        for (int hh = 0; hh < 4; hh++)
          abuf[w][hh][l4 * 4 + r][nt * 16 + l15] = f2b(sacc[hh][nt][r] * rinv);
      }
    // ---- o += attn @ v ----
#pragma unroll
    for (int hh = 0; hh < 4; hh++) {
      const bfrag8 af = *(const bfrag8*)&abuf[w][hh][l15][l4 * 8];
      const unsigned short* vh = vB + (hh << 16);
#pragma unroll
      for (int nt = 0; nt < 4; nt++) {
        const bfrag8 vf = *(const bfrag8*)(vh + (size_t)(nt * 16 + l15) * 1024 + s0 + l4 * 8);
        oacc[hh][nt] = __builtin_amdgcn_mfma_f32_16x16x32_bf16(af, vf, oacc[hh][nt], 0, 0, 0);
      }
    }
  }
  // ---- bf16 partial O through the inverse view ----
  unsigned short* P = (sp == 0) ? P0 : (sp == 1) ? P1 : (sp == 2) ? P2 : P3;
#pragma unroll
  for (int hh = 0; hh < 4; hh++) {
    const size_t rb = ((size_t)nb * 1024 + (size_t)(w * 4 + hh) * 64 + tile) * 1024;
#pragma unroll
    for (int nt = 0; nt < 4; nt++)
#pragma unroll
      for (int r = 0; r < 4; r++)
        P[rb + (size_t)(l4 * 4 + r) * 64 + nt * 16 + l15] = f2b(oacc[hh][nt][r]);
  }
}

// ---------------- reduce 4 bf16 partials -> bf16 ----------------
__global__ __launch_bounds__(256)
void reduce_o4(const unsigned short* __restrict__ P0, const unsigned short* __restrict__ P1,
               const unsigned short* __restrict__ P2, const unsigned short* __restrict__ P3,
               unsigned short* __restrict__ OB, int n4) {
  const int i = blockIdx.x * 256 + threadIdx.x;
  if (i < n4) {
    const ushort4 a = ((const ushort4*)P0)[i];
    const ushort4 b = ((const ushort4*)P1)[i];
    const ushort4 c = ((const ushort4*)P2)[i];
    const ushort4 d = ((const ushort4*)P3)[i];
    ushort4 u;
    u.x = f2b(b2f(a.x) + b2f(b.x) + b2f(c.x) + b2f(d.x));
    u.y = f2b(b2f(a.y) + b2f(b.y) + b2f(c.y) + b2f(d.y));
    u.z = f2b(b2f(a.z) + b2f(b.z) + b2f(c.z) + b2f(d.z));
    u.w = f2b(b2f(a.w) + b2f(b.w) + b2f(c.w) + b2f(d.w));
    ((ushort4*)OB)[i] = u;
  }
}

// ---- LayerNorm reducing 4 bf16 GEMM partials + bias + residual: out = LN(sum+b+res) ----
__global__ __launch_bounds__(256)
void ln_red(const unsigned short* __restrict__ P0, const unsigned short* __restrict__ P1,
            const unsigned short* __restrict__ P2, const unsigned short* __restrict__ P3,
            const float* __restrict__ bias, const float* __restrict__ resid,
            const float* __restrict__ g, const float* __restrict__ be,
            float* __restrict__ outf, unsigned short* __restrict__ outb) {
  const int row = blockIdx.x, tid = threadIdx.x;
  const size_t o4 = (size_t)row * 256 + tid;
  const ushort4 a = ((const ushort4*)P0)[o4];
  const ushort4 b = ((const ushort4*)P1)[o4];
  const ushort4 c = ((const ushort4*)P2)[o4];
  const ushort4 d = ((const ushort4*)P3)[o4];
  const float4 vb = ((const float4*)bias)[tid];
  const float4 vr = ((const float4*)resid)[o4];
  float t0 = b2f(a.x) + b2f(b.x) + b2f(c.x) + b2f(d.x) + vb.x + vr.x;
  float t1 = b2f(a.y) + b2f(b.y) + b2f(c.y) + b2f(d.y) + vb.y + vr.y;
  float t2 = b2f(a.z) + b2f(b.z) + b2f(c.z) + b2f(d.z) + vb.z + vr.z;
  float t3 = b2f(a.w) + b2f(b.w) + b2f(c.w) + b2f(d.w) + vb.w + vr.w;
  float s = t0 + t1 + t2 + t3;
  float q = t0 * t0 + t1 * t1 + t2 * t2 + t3 * t3;
#pragma unroll
  for (int off = 32; off > 0; off >>= 1) {
    s += __shfl_down(s, off, 64);
    q += __shfl_down(q, off, 64);
  }
  __shared__ float rs_[4], rq_[4];
  if ((tid & 63) == 0) { rs_[tid >> 6] = s; rq_[tid >> 6] = q; }
  __syncthreads();
  const float S = rs_[0] + rs_[1] + rs_[2] + rs_[3];
  const float Q = rq_[0] + rq_[1] + rq_[2] + rq_[3];
  const float mean = S * (1.f / 1024.f);
  const float var  = Q * (1.f / 1024.f) - mean * mean;
  const float rstd = rsqrtf(var + 1e-5f);
  const float4 vg  = ((const float4*)g)[tid];
  const float4 vbe = ((const float4*)be)[tid];
  float o0 = (t0 - mean) * rstd * vg.x + vbe.x;
  float o1 = (t1 - mean) * rstd * vg.y + vbe.y;
  float o2 = (t2 - mean) * rstd * vg.z + vbe.z;
  float o3 = (t3 - mean) * rstd * vg.w + vbe.w;
  ((float4*)(outf + (size_t)row * 1024))[tid] = make_float4(o0, o1, o2, o3);
  if (outb != nullptr) {
    ushort4 u;
    u.x = f2b(o0); u.y = f2b(o1); u.z = f2b(o2); u.w = f2b(o3);
    ((ushort4*)(outb + (size_t)row * 1024))[tid] = u;
  }
}

// ---------------- launch ----------------
extern "C" void kernel_launch(void* const* d_in, const int* in_sizes, int n_in,
                              void* d_out, int out_size, void* d_ws, size_t ws_size,
                              hipStream_t stream) {
  const float* x  = (const float*)d_in[0];
  const float* Wq = (const float*)d_in[1];
  const float* bq = (const float*)d_in[2];
  const float* Wk = (const float*)d_in[3];
  const float* bk = (const float*)d_in[4];
  const float* Wv = (const float*)d_in[5];
  const float* bv = (const float*)d_in[6];
  const float* Wo = (const float*)d_in[7];
  const float* bo = (const float*)d_in[8];
  const float* g1 = (const float*)d_in[9];
  const float* b1 = (const float*)d_in[10];
  const float* W1 = (const float*)d_in[11];
  const float* c1 = (const float*)d_in[12];
  const float* W2 = (const float*)d_in[13];
  const float* c2 = (const float*)d_in[14];
  const float* g2 = (const float*)d_in[15];
  const float* b2 = (const float*)d_in[16];
  float* out = (float*)d_out;

  char* ws = (char*)d_ws;
  unsigned short* XB  = (unsigned short*)(ws);              // 8MB  x bf16
  unsigned short* WQT = (unsigned short*)(ws + 8388608);    // 2MB
  unsigned short* WKT = (unsigned short*)(ws + 10485760);   // 2MB
  unsigned short* WVT = (unsigned short*)(ws + 12582912);   // 2MB
  unsigned short* WOT = (unsigned short*)(ws + 14680064);   // 2MB
  unsigned short* W1T = (unsigned short*)(ws + 16777216);   // 8MB
  unsigned short* W2T = (unsigned short*)(ws + 25165824);   // 8MB
  float*          X1  = (float*)(ws + 33554432);            // 16MB fp32 (LN1 out)
  unsigned short* X1B = (unsigned short*)(ws + 50331648);   // 8MB
  char* RB = ws + 58720256;                                 // 48MB union region
  unsigned short* QB  = (unsigned short*)(RB);              // 8MB
  unsigned short* KB  = (unsigned short*)(RB + 8388608);    // 8MB
  unsigned short* VT  = (unsigned short*)(RB + 16777216);   // 8MB
  unsigned short* OB  = (unsigned short*)(RB + 25165824);   // 8MB
  unsigned short* H1B = (unsigned short*)(RB);              // 32MB FFN phase (= QB..OB)
  // attn bf16 partials: dead OWO(16MB)+X1(16MB) regions, 8MB each
  unsigned short* AP0 = (unsigned short*)(RB + 33554432);
  unsigned short* AP1 = (unsigned short*)(RB + 41943040);
  unsigned short* AP2 = (unsigned short*)(ws + 33554432);
  unsigned short* AP3 = (unsigned short*)(ws + 41943040);
  // o-proj split-K partials (QB/KB/VT free after attn; XB free after QKV)
  PtrQuad OPQ = { { QB, KB, VT, XB } };
  // FFN2 split-K partials (XB,X1B free; OWO region free)
  PtrQuad FPQ = { { XB, X1B, (unsigned short*)(RB + 33554432),
                    (unsigned short*)(RB + 41943040) } };
  PtrQuad ZQ = { { nullptr, nullptr, nullptr, nullptr } };

  const dim3 tb(256);
  cvt_bf16_kernel<<<dim3(4096), tb, 0, stream>>>(x, XB, 1048576);
  transpose_cvt<<<dim3(32, 32),  tb, 0, stream>>>(Wq, WQT, 1024, 1024);
  transpose_cvt<<<dim3(32, 32),  tb, 0, stream>>>(Wk, WKT, 1024, 1024);
  transpose_cvt<<<dim3(32, 32),  tb, 0, stream>>>(Wv, WVT, 1024, 1024);
  transpose_cvt<<<dim3(32, 32),  tb, 0, stream>>>(Wo, WOT, 1024, 1024);
  transpose_cvt<<<dim3(128, 32), tb, 0, stream>>>(W1, W1T, 1024, 4096);
  transpose_cvt<<<dim3(32, 128), tb, 0, stream>>>(W2, W2T, 4096, 1024);
  // QKV (N=3072): epilogue scatters Q(scaled), K, V(per-head transposed)
  gemm_bt<EPI_QKV><<<dim3(24, 32), tb, 0, stream>>>(XB, WQT, bq, bk, bv, (void*)QB, ZQ,
                                                    4096, 3072, 1024, 1024);
  // attention: 1024 blocks, 4 s-splits, bf16 partials
  attn_kernel<<<dim3(64, 4, 4), tb, 0, stream>>>(QB, KB, VT, AP0, AP1, AP2, AP3);
  reduce_o4<<<dim3(4096), tb, 0, stream>>>(AP0, AP1, AP2, AP3, OB, 1048576);
  // O-proj: split-K=4 (kLen 256) -> bf16 partials; reduce+bias+residual fused in LN1
  gemm_bt<EPI_PART><<<dim3(8, 32, 4), tb, 0, stream>>>(OB, WOT, nullptr, nullptr, nullptr,
                                                       nullptr, OPQ, 4096, 1024, 256, 1024);
  ln_red<<<dim3(4096), tb, 0, stream>>>(QB, KB, VT, XB, bo, x, g1, b1, X1, X1B);
  // FFN1 + exact GELU -> bf16
  gemm_bt<EPI_GELU><<<dim3(32, 32), tb, 0, stream>>>(X1B, W1T, c1, nullptr, nullptr,
                                                     (void*)H1B, ZQ, 4096, 4096, 1024, 1024);
  // FFN2: split-K=4 (kLen 1024) -> bf16 partials; reduce+bias+residual fused in LN2
  gemm_bt<EPI_PART><<<dim3(8, 32, 4), tb, 0, stream>>>(H1B, W2T, nullptr, nullptr, nullptr,
                                                       nullptr, FPQ, 4096, 1024, 1024, 4096);
  ln_red<<<dim3(4096), tb, 0, stream>>>(FPQ.p[0], FPQ.p[1], FPQ.p[2], FPQ.p[3], c2, X1,
                                        g2, b2, out, (unsigned short*)nullptr);
}

// Round 4
// 512.773 us; speedup vs baseline: 1.0214x; 1.0214x over previous
//
#include <hip/hip_runtime.h>
#include <cstdint>
#include <cstddef>

#define EPI_QKV  0
#define EPI_F32  2
#define EPI_GELU 3
#define EPI_PART 4

typedef __attribute__((ext_vector_type(8))) short bfrag8;   // 8 bf16 (4 VGPRs)
typedef __attribute__((ext_vector_type(4))) float facc4;    // 4 fp32 acc

struct PtrQuad { unsigned short* p[4]; };

__device__ __forceinline__ unsigned short f2b(float x) {
  unsigned int u = __builtin_bit_cast(unsigned int, x);
  u += 0x7FFFu + ((u >> 16) & 1u);   // RNE
  return (unsigned short)(u >> 16);
}
__device__ __forceinline__ float b2f(unsigned short u) {
  unsigned int x = ((unsigned int)u) << 16;
  return __builtin_bit_cast(float, x);
}

__device__ __forceinline__ void gl2lds16(const unsigned short* g, unsigned short* l) {
  __builtin_amdgcn_global_load_lds(
      (const __attribute__((address_space(1))) unsigned int*)g,
      (__attribute__((address_space(3))) unsigned int*)l, 16, 0, 0);
}

// ---------------- elementwise fp32 -> bf16 ----------------
__global__ __launch_bounds__(256)
void cvt_bf16_kernel(const float* __restrict__ in, unsigned short* __restrict__ out, int n4) {
  const int i = blockIdx.x * 256 + threadIdx.x;
  if (i < n4) {
    const float4 v = ((const float4*)in)[i];
    ushort4 u;
    u.x = f2b(v.x); u.y = f2b(v.y); u.z = f2b(v.z); u.w = f2b(v.w);
    ((ushort4*)out)[i] = u;
  }
}

// ---------------- transpose + convert: in (K x N) fp32 -> out (N x K) bf16 ----------------
__global__ __launch_bounds__(256)
void transpose_cvt(const float* __restrict__ in, unsigned short* __restrict__ out,
                   int K, int N) {
  __shared__ float tile[32][33];
  const int n0 = blockIdx.x * 32;
  const int k0 = blockIdx.y * 32;
  const int tx = threadIdx.x & 31, ty = threadIdx.x >> 5;  // ty 0..7
#pragma unroll
  for (int i = 0; i < 32; i += 8)
    tile[ty + i][tx] = in[(size_t)(k0 + ty + i) * N + n0 + tx];
  __syncthreads();
#pragma unroll
  for (int i = 0; i < 32; i += 8)
    out[(size_t)(n0 + ty + i) * K + k0 + tx] = f2b(tile[tx][ty + i]);
}

// ---------------- GEMM: C = A(MxK') @ Bt(NxK')^T slice, bf16 MFMA, fused epilogues ------
// 128x128 tile, BK=32, 4 waves (2x2), 4x4 16x16x32 MFMA per wave. m97 structure.
// K = k-length of this z-slice (k offset = blockIdx.z*K); ldk = full row stride of A/Bt.
template<int EPI>
__global__ __launch_bounds__(256, 2)
void gemm_bt(const unsigned short* __restrict__ A,
             const unsigned short* __restrict__ Bt,
             const float* __restrict__ bias,
             const float* __restrict__ bias2,
             const float* __restrict__ bias3,
             void* __restrict__ out, PtrQuad pq,
             int M, int N, int K, int ldk) {
  __shared__ unsigned short sA[128 * 32];
  __shared__ unsigned short sB[128 * 32];
  const int tid  = threadIdx.x;
  const int lane = tid & 63;
  const int wave = tid >> 6;
  const int l15  = lane & 15, l4 = lane >> 4;
  const int wr = wave >> 1, wc = wave & 1;
  const long row0 = (long)blockIdx.y * 128;
  const long col0 = (long)blockIdx.x * 128;
  const long k0   = (long)blockIdx.z * K;

  facc4 acc[4][4];
#pragma unroll
  for (int i = 0; i < 4; i++)
#pragma unroll
    for (int j = 0; j < 4; j++) acc[i][j] = (facc4)0.f;

  const int srow = tid >> 2;
  const int scol = (tid & 3) * 8;
  const unsigned short* Ap0 = A  + (row0 + srow) * (long)ldk + k0 + scol;
  const unsigned short* Ap1 = Ap0 + 64 * (long)ldk;
  const unsigned short* Bp0 = Bt + (col0 + srow) * (long)ldk + k0 + scol;
  const unsigned short* Bp1 = Bp0 + 64 * (long)ldk;
  const int wbase = (tid & ~63) * 8;
  unsigned short* sA0 = &sA[wbase];
  unsigned short* sA1 = &sA[2048 + wbase];
  unsigned short* sB0 = &sB[wbase];
  unsigned short* sB1 = &sB[2048 + wbase];

  const int aoff = (wr * 64 + l15) * 32 + l4 * 8;
  const int boff = (wc * 64 + l15) * 32 + l4 * 8;

  for (int kt = 0; kt < K; kt += 32) {
    gl2lds16(Ap0 + kt, sA0);
    gl2lds16(Ap1 + kt, sA1);
    gl2lds16(Bp0 + kt, sB0);
    gl2lds16(Bp1 + kt, sB1);
    __syncthreads();
    bfrag8 af[4], bf[4];
#pragma unroll
    for (int i = 0; i < 4; i++) af[i] = *(const bfrag8*)&sA[aoff + i * 512];
#pragma unroll
    for (int j = 0; j < 4; j++) bf[j] = *(const bfrag8*)&sB[boff + j * 512];
#pragma unroll
    for (int i = 0; i < 4; i++)
#pragma unroll
      for (int j = 0; j < 4; j++)
        acc[i][j] = __builtin_amdgcn_mfma_f32_16x16x32_bf16(af[i], bf[j], acc[i][j], 0, 0, 0);
    __syncthreads();
  }

#pragma unroll
  for (int i = 0; i < 4; i++) {
    const long m0 = row0 + wr * 64 + i * 16 + l4 * 4;
#pragma unroll
    for (int j = 0; j < 4; j++) {
      const long c = col0 + wc * 64 + j * 16 + l15;
      if constexpr (EPI == EPI_QKV) {
        const long which = c >> 10;
        const long cl = c & 1023;
        unsigned short* oq = (unsigned short*)out;
        if (which == 0) {
          const float bj = bias[cl];
#pragma unroll
          for (int r = 0; r < 4; r++)
            oq[(m0 + r) * 1024 + cl] = f2b((acc[i][j][r] + bj) * 0.03125f);
        } else if (which == 1) {
          const float bj = bias2[cl];
#pragma unroll
          for (int r = 0; r < 4; r++)
            (oq + 4194304)[(m0 + r) * 1024 + cl] = f2b(acc[i][j][r] + bj);
        } else {
          const float bj = bias3[cl];
          const long cc = cl >> 6, d = cl & 63;
#pragma unroll
          for (int r = 0; r < 4; r++) {
            const long m = m0 + r;
            const long nbb = m >> 10, rr = m & 1023;
            const long h = rr >> 6, rhi = rr & 63;
            const long s = rhi * 16 + cc;
            (oq + 8388608)[((nbb * 16 + h) * 64 + d) * 1024 + s] = f2b(acc[i][j][r] + bj);
          }
        }
      } else if constexpr (EPI == EPI_F32) {
        const float bj = bias[c];
        float* of = (float*)out;
#pragma unroll
        for (int r = 0; r < 4; r++) of[(m0 + r) * (long)N + c] = acc[i][j][r] + bj;
      } else if constexpr (EPI == EPI_PART) {
        unsigned short* ob = pq.p[blockIdx.z];
#pragma unroll
        for (int r = 0; r < 4; r++) ob[(m0 + r) * (long)N + c] = f2b(acc[i][j][r]);
      } else {  // EPI_GELU -> bf16
        const float bj = bias[c];
        unsigned short* ob = (unsigned short*)out;
#pragma unroll
        for (int r = 0; r < 4; r++) {
          const float t = acc[i][j][r] + bj;
          ob[(m0 + r) * (long)N + c] = f2b(0.5f * t * (1.f + erff(t * 0.70710678f)));
        }
      }
    }
  }
}

// ---------------- fused attention v4 (softmax over HEADS at each (t,s)) ----------------
// 1D grid 1024: id = tile*16 + combo, combo = nb + 4*sp. Since 16 ≡ 0 (mod 8 XCDs),
// XCD = combo % 8 is constant per (nb,sp) slice -> each XCD's L2 holds ONE batch's Q
// (2 MB) + two K/V quarter-slices (2 MB). 4 waves x 4 heads; t-tile 16; s-chunks of 32.
// Qb/Kb per-head (s,d) (Q pre-scaled 1/32); Vt per-head (d,s). bf16 partial O out.
__global__ __launch_bounds__(256, 4)
void attn_kernel(const unsigned short* __restrict__ Qb,
                 const unsigned short* __restrict__ Kb,
                 const unsigned short* __restrict__ Vt,
                 unsigned short* __restrict__ P0, unsigned short* __restrict__ P1,
                 unsigned short* __restrict__ P2, unsigned short* __restrict__ P3) {
  const int id = blockIdx.x;
  const int combo = id & 15;
  const int tile = id >> 4;
  const int nb = combo & 3;
  const int sp = combo >> 2;
  const int tid = threadIdx.x, lane = tid & 63;
  const int w = __builtin_amdgcn_readfirstlane(tid >> 6);   // wave id in SGPR
  const int l15 = lane & 15, l4 = lane >> 4;
  const int t0 = tile * 16;

  __shared__ float red[2][4][576];                     // dbuf head-sum exchange, 18 KB
  __shared__ __align__(16) unsigned short abuf[4][4][16][40];  // wave-private attn, 20 KB

  const unsigned short* qB = Qb + ((size_t)(nb * 16 + w * 4) << 16);
  const unsigned short* kB = Kb + ((size_t)(nb * 16 + w * 4) << 16);
  const unsigned short* vB = Vt + ((size_t)(nb * 16 + w * 4) << 16);

  // persistent Q A-frags: [head][ks] (32 VGPRs) — constant over the s loop
  bfrag8 qf[4][2];
#pragma unroll
  for (int hh = 0; hh < 4; hh++)
#pragma unroll
    for (int ks = 0; ks < 2; ks++)
      qf[hh][ks] = *(const bfrag8*)(qB + (hh << 16) + (t0 + l15) * 64 + ks * 32 + l4 * 8);

  facc4 oacc[4][4];
#pragma unroll
  for (int hh = 0; hh < 4; hh++)
#pragma unroll
    for (int nt = 0; nt < 4; nt++) oacc[hh][nt] = (facc4)0.f;

  for (int it = 0; it < 8; ++it) {
    const int s0 = sp * 256 + it * 32;
    const int pb = it & 1;
    // ---- QK^T scores for 4 heads, 16t x 32s ----
    facc4 sacc[4][2];
#pragma unroll
    for (int hh = 0; hh < 4; hh++)
#pragma unroll
      for (int nt = 0; nt < 2; nt++) sacc[hh][nt] = (facc4)0.f;
#pragma unroll
    for (int hh = 0; hh < 4; hh++) {
      const unsigned short* kh = kB + (hh << 16);
#pragma unroll
      for (int ks = 0; ks < 2; ks++)
#pragma unroll
        for (int nt = 0; nt < 2; nt++) {
          const bfrag8 kf = *(const bfrag8*)(kh + (s0 + nt * 16 + l15) * 64 + ks * 32 + l4 * 8);
          sacc[hh][nt] = __builtin_amdgcn_mfma_f32_16x16x32_bf16(qf[hh][ks], kf, sacc[hh][nt], 0, 0, 0);
        }
    }
    // ---- exp + this wave's 4-head partial sums -> red[pb][w] ----
#pragma unroll
    for (int nt = 0; nt < 2; nt++)
#pragma unroll
      for (int r = 0; r < 4; r++) {
        float s = 0.f;
#pragma unroll
        for (int hh = 0; hh < 4; hh++) {
          const float e = __expf(sacc[hh][nt][r]);
          sacc[hh][nt][r] = e;
          s += e;
        }
        red[pb][w][(l4 * 4 + r) * 36 + nt * 16 + l15] = s;
      }
    __syncthreads();
    // ---- full 16-head sum, normalize -> bf16 -> wave-private abuf ----
#pragma unroll
    for (int nt = 0; nt < 2; nt++)
#pragma unroll
      for (int r = 0; r < 4; r++) {
        const int o = (l4 * 4 + r) * 36 + nt * 16 + l15;
        const float rinv =
            1.f / (red[pb][0][o] + red[pb][1][o] + red[pb][2][o] + red[pb][3][o]);
#pragma unroll
        for (int hh = 0; hh < 4; hh++)
          abuf[w][hh][l4 * 4 + r][nt * 16 + l15] = f2b(sacc[hh][nt][r] * rinv);
      }
    // ---- o += attn @ v ----
#pragma unroll
    for (int hh = 0; hh < 4; hh++) {
      const bfrag8 af = *(const bfrag8*)&abuf[w][hh][l15][l4 * 8];
      const unsigned short* vh = vB + (hh << 16);
#pragma unroll
      for (int nt = 0; nt < 4; nt++) {
        const bfrag8 vf = *(const bfrag8*)(vh + (size_t)(nt * 16 + l15) * 1024 + s0 + l4 * 8);
        oacc[hh][nt] = __builtin_amdgcn_mfma_f32_16x16x32_bf16(af, vf, oacc[hh][nt], 0, 0, 0);
      }
    }
  }
  // ---- bf16 partial O through the inverse view ----
  unsigned short* P = (sp == 0) ? P0 : (sp == 1) ? P1 : (sp == 2) ? P2 : P3;
#pragma unroll
  for (int hh = 0; hh < 4; hh++) {
    const size_t rb = ((size_t)nb * 1024 + (size_t)(w * 4 + hh) * 64 + tile) * 1024;
#pragma unroll
    for (int nt = 0; nt < 4; nt++)
#pragma unroll
      for (int r = 0; r < 4; r++)
        P[rb + (size_t)(l4 * 4 + r) * 64 + nt * 16 + l15] = f2b(oacc[hh][nt][r]);
  }
}

// ---------------- reduce 4 bf16 partials -> bf16 ----------------
__global__ __launch_bounds__(256)
void reduce_o4(const unsigned short* __restrict__ P0, const unsigned short* __restrict__ P1,
               const unsigned short* __restrict__ P2, const unsigned short* __restrict__ P3,
               unsigned short* __restrict__ OB, int n4) {
  const int i = blockIdx.x * 256 + threadIdx.x;
  if (i < n4) {
    const ushort4 a = ((const ushort4*)P0)[i];
    const ushort4 b = ((const ushort4*)P1)[i];
    const ushort4 c = ((const ushort4*)P2)[i];
    const ushort4 d = ((const ushort4*)P3)[i];
    ushort4 u;
    u.x = f2b(b2f(a.x) + b2f(b.x) + b2f(c.x) + b2f(d.x));
    u.y = f2b(b2f(a.y) + b2f(b.y) + b2f(c.y) + b2f(d.y));
    u.z = f2b(b2f(a.z) + b2f(b.z) + b2f(c.z) + b2f(d.z));
    u.w = f2b(b2f(a.w) + b2f(b.w) + b2f(c.w) + b2f(d.w));
    ((ushort4*)OB)[i] = u;
  }
}

// ---- LayerNorm reducing 4 bf16 GEMM partials + bias + residual: out = LN(sum+b+res) ----
__global__ __launch_bounds__(256)
void ln_red(const unsigned short* __restrict__ P0, const unsigned short* __restrict__ P1,
            const unsigned short* __restrict__ P2, const unsigned short* __restrict__ P3,
            const float* __restrict__ bias, const float* __restrict__ resid,
            const float* __restrict__ g, const float* __restrict__ be,
            float* __restrict__ outf, unsigned short* __restrict__ outb) {
  const int row = blockIdx.x, tid = threadIdx.x;
  const size_t o4 = (size_t)row * 256 + tid;
  const ushort4 a = ((const ushort4*)P0)[o4];
  const ushort4 b = ((const ushort4*)P1)[o4];
  const ushort4 c = ((const ushort4*)P2)[o4];
  const ushort4 d = ((const ushort4*)P3)[o4];
  const float4 vb = ((const float4*)bias)[tid];
  const float4 vr = ((const float4*)resid)[o4];
  float t0 = b2f(a.x) + b2f(b.x) + b2f(c.x) + b2f(d.x) + vb.x + vr.x;
  float t1 = b2f(a.y) + b2f(b.y) + b2f(c.y) + b2f(d.y) + vb.y + vr.y;
  float t2 = b2f(a.z) + b2f(b.z) + b2f(c.z) + b2f(d.z) + vb.z + vr.z;
  float t3 = b2f(a.w) + b2f(b.w) + b2f(c.w) + b2f(d.w) + vb.w + vr.w;
  float s = t0 + t1 + t2 + t3;
  float q = t0 * t0 + t1 * t1 + t2 * t2 + t3 * t3;
#pragma unroll
  for (int off = 32; off > 0; off >>= 1) {
    s += __shfl_down(s, off, 64);
    q += __shfl_down(q, off, 64);
  }
  __shared__ float rs_[4], rq_[4];
  if ((tid & 63) == 0) { rs_[tid >> 6] = s; rq_[tid >> 6] = q; }
  __syncthreads();
  const float S = rs_[0] + rs_[1] + rs_[2] + rs_[3];
  const float Q = rq_[0] + rq_[1] + rq_[2] + rq_[3];
  const float mean = S * (1.f / 1024.f);
  const float var  = Q * (1.f / 1024.f) - mean * mean;
  const float rstd = rsqrtf(var + 1e-5f);
  const float4 vg  = ((const float4*)g)[tid];
  const float4 vbe = ((const float4*)be)[tid];
  float o0 = (t0 - mean) * rstd * vg.x + vbe.x;
  float o1 = (t1 - mean) * rstd * vg.y + vbe.y;
  float o2 = (t2 - mean) * rstd * vg.z + vbe.z;
  float o3 = (t3 - mean) * rstd * vg.w + vbe.w;
  ((float4*)(outf + (size_t)row * 1024))[tid] = make_float4(o0, o1, o2, o3);
  if (outb != nullptr) {
    ushort4 u;
    u.x = f2b(o0); u.y = f2b(o1); u.z = f2b(o2); u.w = f2b(o3);
    ((ushort4*)(outb + (size_t)row * 1024))[tid] = u;
  }
}

// ---------------- launch ----------------
extern "C" void kernel_launch(void* const* d_in, const int* in_sizes, int n_in,
                              void* d_out, int out_size, void* d_ws, size_t ws_size,
                              hipStream_t stream) {
  const float* x  = (const float*)d_in[0];
  const float* Wq = (const float*)d_in[1];
  const float* bq = (const float*)d_in[2];
  const float* Wk = (const float*)d_in[3];
  const float* bk = (const float*)d_in[4];
  const float* Wv = (const float*)d_in[5];
  const float* bv = (const float*)d_in[6];
  const float* Wo = (const float*)d_in[7];
  const float* bo = (const float*)d_in[8];
  const float* g1 = (const float*)d_in[9];
  const float* b1 = (const float*)d_in[10];
  const float* W1 = (const float*)d_in[11];
  const float* c1 = (const float*)d_in[12];
  const float* W2 = (const float*)d_in[13];
  const float* c2 = (const float*)d_in[14];
  const float* g2 = (const float*)d_in[15];
  const float* b2 = (const float*)d_in[16];
  float* out = (float*)d_out;

  char* ws = (char*)d_ws;
  unsigned short* XB  = (unsigned short*)(ws);              // 8MB  x bf16
  unsigned short* WQT = (unsigned short*)(ws + 8388608);    // 2MB
  unsigned short* WKT = (unsigned short*)(ws + 10485760);   // 2MB
  unsigned short* WVT = (unsigned short*)(ws + 12582912);   // 2MB
  unsigned short* WOT = (unsigned short*)(ws + 14680064);   // 2MB
  unsigned short* W1T = (unsigned short*)(ws + 16777216);   // 8MB
  unsigned short* W2T = (unsigned short*)(ws + 25165824);   // 8MB
  float*          X1  = (float*)(ws + 33554432);            // 16MB fp32 (LN1 out)
  unsigned short* X1B = (unsigned short*)(ws + 50331648);   // 8MB
  char* RB = ws + 58720256;                                 // 48MB union region
  unsigned short* QB  = (unsigned short*)(RB);              // 8MB
  unsigned short* KB  = (unsigned short*)(RB + 8388608);    // 8MB
  unsigned short* VT  = (unsigned short*)(RB + 16777216);   // 8MB
  unsigned short* OB  = (unsigned short*)(RB + 25165824);   // 8MB
  unsigned short* H1B = (unsigned short*)(RB);              // 32MB FFN phase (= QB..OB)
  // attn bf16 partials: dead OWO(16MB)+X1(16MB) regions, 8MB each
  unsigned short* AP0 = (unsigned short*)(RB + 33554432);
  unsigned short* AP1 = (unsigned short*)(RB + 41943040);
  unsigned short* AP2 = (unsigned short*)(ws + 33554432);
  unsigned short* AP3 = (unsigned short*)(ws + 41943040);
  // o-proj split-K partials (QB/KB/VT free after attn; XB free after QKV)
  PtrQuad OPQ = { { QB, KB, VT, XB } };
  // FFN2 split-K partials (XB,X1B free; OWO region free)
  PtrQuad FPQ = { { XB, X1B, (unsigned short*)(RB + 33554432),
                    (unsigned short*)(RB + 41943040) } };
  PtrQuad ZQ = { { nullptr, nullptr, nullptr, nullptr } };

  const dim3 tb(256);
  cvt_bf16_kernel<<<dim3(4096), tb, 0, stream>>>(x, XB, 1048576);
  transpose_cvt<<<dim3(32, 32),  tb, 0, stream>>>(Wq, WQT, 1024, 1024);
  transpose_cvt<<<dim3(32, 32),  tb, 0, stream>>>(Wk, WKT, 1024, 1024);
  transpose_cvt<<<dim3(32, 32),  tb, 0, stream>>>(Wv, WVT, 1024, 1024);
  transpose_cvt<<<dim3(32, 32),  tb, 0, stream>>>(Wo, WOT, 1024, 1024);
  transpose_cvt<<<dim3(128, 32), tb, 0, stream>>>(W1, W1T, 1024, 4096);
  transpose_cvt<<<dim3(32, 128), tb, 0, stream>>>(W2, W2T, 4096, 1024);
  // QKV (N=3072): epilogue scatters Q(scaled), K, V(per-head transposed)
  gemm_bt<EPI_QKV><<<dim3(24, 32), tb, 0, stream>>>(XB, WQT, bq, bk, bv, (void*)QB, ZQ,
                                                    4096, 3072, 1024, 1024);
  // attention: 1D grid 1024, XCD-pinned (nb,sp) slices, bf16 partials
  attn_kernel<<<dim3(1024), tb, 0, stream>>>(QB, KB, VT, AP0, AP1, AP2, AP3);
  reduce_o4<<<dim3(4096), tb, 0, stream>>>(AP0, AP1, AP2, AP3, OB, 1048576);
  // O-proj: split-K=4 (kLen 256) -> bf16 partials; reduce+bias+residual fused in LN1
  gemm_bt<EPI_PART><<<dim3(8, 32, 4), tb, 0, stream>>>(OB, WOT, nullptr, nullptr, nullptr,
                                                       nullptr, OPQ, 4096, 1024, 256, 1024);
  ln_red<<<dim3(4096), tb, 0, stream>>>(QB, KB, VT, XB, bo, x, g1, b1, X1, X1B);
  // FFN1 + exact GELU -> bf16
  gemm_bt<EPI_GELU><<<dim3(32, 32), tb, 0, stream>>>(X1B, W1T, c1, nullptr, nullptr,
                                                     (void*)H1B, ZQ, 4096, 4096, 1024, 1024);
  // FFN2: split-K=4 (kLen 1024) -> bf16 partials; reduce+bias+residual fused in LN2
  gemm_bt<EPI_PART><<<dim3(8, 32, 4), tb, 0, stream>>>(H1B, W2T, nullptr, nullptr, nullptr,
                                                       nullptr, FPQ, 4096, 1024, 1024, 4096);
  ln_red<<<dim3(4096), tb, 0, stream>>>(FPQ.p[0], FPQ.p[1], FPQ.p[2], FPQ.p[3], c2, X1,
                                        g2, b2, out, (unsigned short*)nullptr);
}

// Round 5
// 468.538 us; speedup vs baseline: 1.1178x; 1.0944x over previous
//
#include <hip/hip_runtime.h>
#include <cstdint>
#include <cstddef>

#define EPI_QKV  0
#define EPI_F32  2
#define EPI_GELU 3
#define EPI_PART 4

typedef __attribute__((ext_vector_type(8))) short bfrag8;   // 8 bf16 (4 VGPRs)
typedef __attribute__((ext_vector_type(4))) float facc4;    // 4 fp32 acc

struct PtrQuad { unsigned short* p[4]; };

__device__ __forceinline__ unsigned short f2b(float x) {
  unsigned int u = __builtin_bit_cast(unsigned int, x);
  u += 0x7FFFu + ((u >> 16) & 1u);   // RNE
  return (unsigned short)(u >> 16);
}
__device__ __forceinline__ float b2f(unsigned short u) {
  unsigned int x = ((unsigned int)u) << 16;
  return __builtin_bit_cast(float, x);
}

__device__ __forceinline__ void gl2lds16(const unsigned short* g, unsigned short* l) {
  __builtin_amdgcn_global_load_lds(
      (const __attribute__((address_space(1))) unsigned int*)g,
      (__attribute__((address_space(3))) unsigned int*)l, 16, 0, 0);
}

// ---------------- elementwise fp32 -> bf16 ----------------
__global__ __launch_bounds__(256)
void cvt_bf16_kernel(const float* __restrict__ in, unsigned short* __restrict__ out, int n4) {
  const int i = blockIdx.x * 256 + threadIdx.x;
  if (i < n4) {
    const float4 v = ((const float4*)in)[i];
    ushort4 u;
    u.x = f2b(v.x); u.y = f2b(v.y); u.z = f2b(v.z); u.w = f2b(v.w);
    ((ushort4*)out)[i] = u;
  }
}

// ---------------- transpose + convert: in (K x N) fp32 -> out (N x K) bf16 ----------------
__global__ __launch_bounds__(256)
void transpose_cvt(const float* __restrict__ in, unsigned short* __restrict__ out,
                   int K, int N) {
  __shared__ float tile[32][33];
  const int n0 = blockIdx.x * 32;
  const int k0 = blockIdx.y * 32;
  const int tx = threadIdx.x & 31, ty = threadIdx.x >> 5;  // ty 0..7
#pragma unroll
  for (int i = 0; i < 32; i += 8)
    tile[ty + i][tx] = in[(size_t)(k0 + ty + i) * N + n0 + tx];
  __syncthreads();
#pragma unroll
  for (int i = 0; i < 32; i += 8)
    out[(size_t)(n0 + ty + i) * K + k0 + tx] = f2b(tile[tx][ty + i]);
}

// ---------------- GEMM: C = A(MxK') @ Bt(NxK')^T slice, bf16 MFMA, fused epilogues ------
// 128x128 tile, BK=32, 4 waves (2x2), 4x4 16x16x32 MFMA per wave. m97 structure.
template<int EPI>
__global__ __launch_bounds__(256, 2)
void gemm_bt(const unsigned short* __restrict__ A,
             const unsigned short* __restrict__ Bt,
             const float* __restrict__ bias,
             const float* __restrict__ bias2,
             const float* __restrict__ bias3,
             void* __restrict__ out, PtrQuad pq,
             int M, int N, int K, int ldk) {
  __shared__ unsigned short sA[128 * 32];
  __shared__ unsigned short sB[128 * 32];
  const int tid  = threadIdx.x;
  const int lane = tid & 63;
  const int wave = tid >> 6;
  const int l15  = lane & 15, l4 = lane >> 4;
  const int wr = wave >> 1, wc = wave & 1;
  const long row0 = (long)blockIdx.y * 128;
  const long col0 = (long)blockIdx.x * 128;
  const long k0   = (long)blockIdx.z * K;

  facc4 acc[4][4];
#pragma unroll
  for (int i = 0; i < 4; i++)
#pragma unroll
    for (int j = 0; j < 4; j++) acc[i][j] = (facc4)0.f;

  const int srow = tid >> 2;
  const int scol = (tid & 3) * 8;
  const unsigned short* Ap0 = A  + (row0 + srow) * (long)ldk + k0 + scol;
  const unsigned short* Ap1 = Ap0 + 64 * (long)ldk;
  const unsigned short* Bp0 = Bt + (col0 + srow) * (long)ldk + k0 + scol;
  const unsigned short* Bp1 = Bp0 + 64 * (long)ldk;
  const int wbase = (tid & ~63) * 8;
  unsigned short* sA0 = &sA[wbase];
  unsigned short* sA1 = &sA[2048 + wbase];
  unsigned short* sB0 = &sB[wbase];
  unsigned short* sB1 = &sB[2048 + wbase];

  const int aoff = (wr * 64 + l15) * 32 + l4 * 8;
  const int boff = (wc * 64 + l15) * 32 + l4 * 8;

  for (int kt = 0; kt < K; kt += 32) {
    gl2lds16(Ap0 + kt, sA0);
    gl2lds16(Ap1 + kt, sA1);
    gl2lds16(Bp0 + kt, sB0);
    gl2lds16(Bp1 + kt, sB1);
    __syncthreads();
    bfrag8 af[4], bf[4];
#pragma unroll
    for (int i = 0; i < 4; i++) af[i] = *(const bfrag8*)&sA[aoff + i * 512];
#pragma unroll
    for (int j = 0; j < 4; j++) bf[j] = *(const bfrag8*)&sB[boff + j * 512];
#pragma unroll
    for (int i = 0; i < 4; i++)
#pragma unroll
      for (int j = 0; j < 4; j++)
        acc[i][j] = __builtin_amdgcn_mfma_f32_16x16x32_bf16(af[i], bf[j], acc[i][j], 0, 0, 0);
    __syncthreads();
  }

#pragma unroll
  for (int i = 0; i < 4; i++) {
    const long m0 = row0 + wr * 64 + i * 16 + l4 * 4;
#pragma unroll
    for (int j = 0; j < 4; j++) {
      const long c = col0 + wc * 64 + j * 16 + l15;
      if constexpr (EPI == EPI_QKV) {
        const long which = c >> 10;
        const long cl = c & 1023;
        unsigned short* oq = (unsigned short*)out;
        if (which == 0) {
          const float bj = bias[cl];
#pragma unroll
          for (int r = 0; r < 4; r++)
            oq[(m0 + r) * 1024 + cl] = f2b((acc[i][j][r] + bj) * 0.03125f);
        } else if (which == 1) {
          const float bj = bias2[cl];
#pragma unroll
          for (int r = 0; r < 4; r++)
            (oq + 4194304)[(m0 + r) * 1024 + cl] = f2b(acc[i][j][r] + bj);
        } else {
          const float bj = bias3[cl];
          const long cc = cl >> 6, d = cl & 63;
#pragma unroll
          for (int r = 0; r < 4; r++) {
            const long m = m0 + r;
            const long nbb = m >> 10, rr = m & 1023;
            const long h = rr >> 6, rhi = rr & 63;
            const long s = rhi * 16 + cc;
            (oq + 8388608)[((nbb * 16 + h) * 64 + d) * 1024 + s] = f2b(acc[i][j][r] + bj);
          }
        }
      } else if constexpr (EPI == EPI_F32) {
        const float bj = bias[c];
        float* of = (float*)out;
#pragma unroll
        for (int r = 0; r < 4; r++) of[(m0 + r) * (long)N + c] = acc[i][j][r] + bj;
      } else if constexpr (EPI == EPI_PART) {
        unsigned short* ob = pq.p[blockIdx.z];
#pragma unroll
        for (int r = 0; r < 4; r++) ob[(m0 + r) * (long)N + c] = f2b(acc[i][j][r]);
      } else {  // EPI_GELU -> bf16
        const float bj = bias[c];
        unsigned short* ob = (unsigned short*)out;
#pragma unroll
        for (int r = 0; r < 4; r++) {
          const float t = acc[i][j][r] + bj;
          ob[(m0 + r) * (long)N + c] = f2b(0.5f * t * (1.f + erff(t * 0.70710678f)));
        }
      }
    }
  }
}

// ---------------- fused attention v5 (softmax over HEADS at each (t,s)) ----------------
// 1D grid 512: id = tile*8 + combo, combo = nb + 4*sp (8 combos = 8 XCDs; tile stride 8
// keeps combo->XCD fixed). Per-XCD L2 set: Q[nb] 2MB + half K/V slices 2MB = 4MB.
// 512 thr = 8 waves x 2 heads; t-tile 16; s-chunks 32 (16 iters). Q pre-scaled 1/32.
// Qb/Kb per-head (s,d); Vt per-head (d,s). bf16 partial O (inverse-view layout).
__global__ __launch_bounds__(512, 4)
void attn_kernel(const unsigned short* __restrict__ Qb,
                 const unsigned short* __restrict__ Kb,
                 const unsigned short* __restrict__ Vt,
                 unsigned short* __restrict__ P0, unsigned short* __restrict__ P1) {
  const int id = blockIdx.x;
  const int combo = id & 7;
  const int tile = id >> 3;
  const int nb = combo & 3;
  const int sp = combo >> 2;
  const int tid = threadIdx.x, lane = tid & 63;
  const int w = __builtin_amdgcn_readfirstlane(tid >> 6);   // wave id 0..7 in SGPR
  const int l15 = lane & 15, l4 = lane >> 4;
  const int t0 = tile * 16;

  // red[pb][o][wave]: wave dim contiguous -> 16-head sum = 2 float4 reads. 36 KB.
  __shared__ __align__(16) float red[2][576][8];
  __shared__ __align__(16) unsigned short abuf[8][2][16][40];  // 20 KB, wave-private

  const size_t hb0 = (size_t)(nb * 16 + w * 2) << 16;
  const unsigned short* qB = Qb + hb0;
  const unsigned short* kB = Kb + hb0;
  const unsigned short* vB = Vt + hb0;

  // persistent Q A-frags (16 VGPRs)
  bfrag8 qf[2][2];
#pragma unroll
  for (int hh = 0; hh < 2; hh++)
#pragma unroll
    for (int ks = 0; ks < 2; ks++)
      qf[hh][ks] = *(const bfrag8*)(qB + (hh << 16) + (t0 + l15) * 64 + ks * 32 + l4 * 8);

  facc4 oacc[2][4];
#pragma unroll
  for (int hh = 0; hh < 2; hh++)
#pragma unroll
    for (int nt = 0; nt < 4; nt++) oacc[hh][nt] = (facc4)0.f;

  for (int it = 0; it < 16; ++it) {
    const int s0 = sp * 512 + it * 32;
    const int pb = it & 1;
    // ---- QK^T scores, 2 heads, 16t x 32s ----
    facc4 sacc[2][2];
#pragma unroll
    for (int hh = 0; hh < 2; hh++)
#pragma unroll
      for (int nt = 0; nt < 2; nt++) sacc[hh][nt] = (facc4)0.f;
#pragma unroll
    for (int hh = 0; hh < 2; hh++) {
      const unsigned short* kh = kB + (hh << 16);
#pragma unroll
      for (int ks = 0; ks < 2; ks++)
#pragma unroll
        for (int nt = 0; nt < 2; nt++) {
          const bfrag8 kf = *(const bfrag8*)(kh + (s0 + nt * 16 + l15) * 64 + ks * 32 + l4 * 8);
          sacc[hh][nt] = __builtin_amdgcn_mfma_f32_16x16x32_bf16(qf[hh][ks], kf, sacc[hh][nt], 0, 0, 0);
        }
    }
    // ---- prefetch head-0 V frags (latency overlapped with exp+barrier) ----
    bfrag8 vf0[4];
#pragma unroll
    for (int nt = 0; nt < 4; nt++)
      vf0[nt] = *(const bfrag8*)(vB + (size_t)(nt * 16 + l15) * 1024 + s0 + l4 * 8);
    // ---- exp + 2-head partial sums -> red[pb][o][w] ----
#pragma unroll
    for (int nt = 0; nt < 2; nt++)
#pragma unroll
      for (int r = 0; r < 4; r++) {
        const float e0 = __expf(sacc[0][nt][r]);
        const float e1 = __expf(sacc[1][nt][r]);
        sacc[0][nt][r] = e0; sacc[1][nt][r] = e1;
        red[pb][(l4 * 4 + r) * 36 + nt * 16 + l15][w] = e0 + e1;
      }
    __syncthreads();
    // ---- 16-head sum via 2x float4, normalize -> bf16 -> wave-private abuf ----
#pragma unroll
    for (int nt = 0; nt < 2; nt++)
#pragma unroll
      for (int r = 0; r < 4; r++) {
        const int o = (l4 * 4 + r) * 36 + nt * 16 + l15;
        const float4 sa = *(const float4*)&red[pb][o][0];
        const float4 sb = *(const float4*)&red[pb][o][4];
        const float rinv = 1.f / (sa.x + sa.y + sa.z + sa.w + sb.x + sb.y + sb.z + sb.w);
        abuf[w][0][l4 * 4 + r][nt * 16 + l15] = f2b(sacc[0][nt][r] * rinv);
        abuf[w][1][l4 * 4 + r][nt * 16 + l15] = f2b(sacc[1][nt][r] * rinv);
      }
    // ---- o += attn @ v ----
    {
      const bfrag8 af0 = *(const bfrag8*)&abuf[w][0][l15][l4 * 8];
#pragma unroll
      for (int nt = 0; nt < 4; nt++)
        oacc[0][nt] = __builtin_amdgcn_mfma_f32_16x16x32_bf16(af0, vf0[nt], oacc[0][nt], 0, 0, 0);
      const bfrag8 af1 = *(const bfrag8*)&abuf[w][1][l15][l4 * 8];
      const unsigned short* vh1 = vB + (1 << 16);
#pragma unroll
      for (int nt = 0; nt < 4; nt++) {
        const bfrag8 vf = *(const bfrag8*)(vh1 + (size_t)(nt * 16 + l15) * 1024 + s0 + l4 * 8);
        oacc[1][nt] = __builtin_amdgcn_mfma_f32_16x16x32_bf16(af1, vf, oacc[1][nt], 0, 0, 0);
      }
    }
  }
  // ---- bf16 partial O through the inverse view ----
  unsigned short* P = sp ? P1 : P0;
#pragma unroll
  for (int hh = 0; hh < 2; hh++) {
    const size_t rb = ((size_t)nb * 1024 + (size_t)(w * 2 + hh) * 64 + tile) * 1024;
#pragma unroll
    for (int nt = 0; nt < 4; nt++)
#pragma unroll
      for (int r = 0; r < 4; r++)
        P[rb + (size_t)(l4 * 4 + r) * 64 + nt * 16 + l15] = f2b(oacc[hh][nt][r]);
  }
}

// ---------------- reduce 2 bf16 partials -> bf16 ----------------
__global__ __launch_bounds__(256)
void reduce_o2(const unsigned short* __restrict__ P0, const unsigned short* __restrict__ P1,
               unsigned short* __restrict__ OB, int n4) {
  const int i = blockIdx.x * 256 + threadIdx.x;
  if (i < n4) {
    const ushort4 a = ((const ushort4*)P0)[i];
    const ushort4 b = ((const ushort4*)P1)[i];
    ushort4 u;
    u.x = f2b(b2f(a.x) + b2f(b.x));
    u.y = f2b(b2f(a.y) + b2f(b.y));
    u.z = f2b(b2f(a.z) + b2f(b.z));
    u.w = f2b(b2f(a.w) + b2f(b.w));
    ((ushort4*)OB)[i] = u;
  }
}

// ---- LayerNorm reducing 4 bf16 GEMM partials + bias + residual: out = LN(sum+b+res) ----
__global__ __launch_bounds__(256)
void ln_red(const unsigned short* __restrict__ P0, const unsigned short* __restrict__ P1,
            const unsigned short* __restrict__ P2, const unsigned short* __restrict__ P3,
            const float* __restrict__ bias, const float* __restrict__ resid,
            const float* __restrict__ g, const float* __restrict__ be,
            float* __restrict__ outf, unsigned short* __restrict__ outb) {
  const int row = blockIdx.x, tid = threadIdx.x;
  const size_t o4 = (size_t)row * 256 + tid;
  const ushort4 a = ((const ushort4*)P0)[o4];
  const ushort4 b = ((const ushort4*)P1)[o4];
  const ushort4 c = ((const ushort4*)P2)[o4];
  const ushort4 d = ((const ushort4*)P3)[o4];
  const float4 vb = ((const float4*)bias)[tid];
  const float4 vr = ((const float4*)resid)[o4];
  float t0 = b2f(a.x) + b2f(b.x) + b2f(c.x) + b2f(d.x) + vb.x + vr.x;
  float t1 = b2f(a.y) + b2f(b.y) + b2f(c.y) + b2f(d.y) + vb.y + vr.y;
  float t2 = b2f(a.z) + b2f(b.z) + b2f(c.z) + b2f(d.z) + vb.z + vr.z;
  float t3 = b2f(a.w) + b2f(b.w) + b2f(c.w) + b2f(d.w) + vb.w + vr.w;
  float s = t0 + t1 + t2 + t3;
  float q = t0 * t0 + t1 * t1 + t2 * t2 + t3 * t3;
#pragma unroll
  for (int off = 32; off > 0; off >>= 1) {
    s += __shfl_down(s, off, 64);
    q += __shfl_down(q, off, 64);
  }
  __shared__ float rs_[4], rq_[4];
  if ((tid & 63) == 0) { rs_[tid >> 6] = s; rq_[tid >> 6] = q; }
  __syncthreads();
  const float S = rs_[0] + rs_[1] + rs_[2] + rs_[3];
  const float Q = rq_[0] + rq_[1] + rq_[2] + rq_[3];
  const float mean = S * (1.f / 1024.f);
  const float var  = Q * (1.f / 1024.f) - mean * mean;
  const float rstd = rsqrtf(var + 1e-5f);
  const float4 vg  = ((const float4*)g)[tid];
  const float4 vbe = ((const float4*)be)[tid];
  float o0 = (t0 - mean) * rstd * vg.x + vbe.x;
  float o1 = (t1 - mean) * rstd * vg.y + vbe.y;
  float o2 = (t2 - mean) * rstd * vg.z + vbe.z;
  float o3 = (t3 - mean) * rstd * vg.w + vbe.w;
  ((float4*)(outf + (size_t)row * 1024))[tid] = make_float4(o0, o1, o2, o3);
  if (outb != nullptr) {
    ushort4 u;
    u.x = f2b(o0); u.y = f2b(o1); u.z = f2b(o2); u.w = f2b(o3);
    ((ushort4*)(outb + (size_t)row * 1024))[tid] = u;
  }
}

// ---------------- launch ----------------
extern "C" void kernel_launch(void* const* d_in, const int* in_sizes, int n_in,
                              void* d_out, int out_size, void* d_ws, size_t ws_size,
                              hipStream_t stream) {
  const float* x  = (const float*)d_in[0];
  const float* Wq = (const float*)d_in[1];
  const float* bq = (const float*)d_in[2];
  const float* Wk = (const float*)d_in[3];
  const float* bk = (const float*)d_in[4];
  const float* Wv = (const float*)d_in[5];
  const float* bv = (const float*)d_in[6];
  const float* Wo = (const float*)d_in[7];
  const float* bo = (const float*)d_in[8];
  const float* g1 = (const float*)d_in[9];
  const float* b1 = (const float*)d_in[10];
  const float* W1 = (const float*)d_in[11];
  const float* c1 = (const float*)d_in[12];
  const float* W2 = (const float*)d_in[13];
  const float* c2 = (const float*)d_in[14];
  const float* g2 = (const float*)d_in[15];
  const float* b2 = (const float*)d_in[16];
  float* out = (float*)d_out;

  char* ws = (char*)d_ws;
  unsigned short* XB  = (unsigned short*)(ws);              // 8MB  x bf16
  unsigned short* WQT = (unsigned short*)(ws + 8388608);    // 2MB
  unsigned short* WKT = (unsigned short*)(ws + 10485760);   // 2MB
  unsigned short* WVT = (unsigned short*)(ws + 12582912);   // 2MB
  unsigned short* WOT = (unsigned short*)(ws + 14680064);   // 2MB
  unsigned short* W1T = (unsigned short*)(ws + 16777216);   // 8MB
  unsigned short* W2T = (unsigned short*)(ws + 25165824);   // 8MB
  float*          X1  = (float*)(ws + 33554432);            // 16MB fp32 (LN1 out)
  unsigned short* X1B = (unsigned short*)(ws + 50331648);   // 8MB
  char* RB = ws + 58720256;                                 // 48MB union region
  unsigned short* QB  = (unsigned short*)(RB);              // 8MB
  unsigned short* KB  = (unsigned short*)(RB + 8388608);    // 8MB
  unsigned short* VT  = (unsigned short*)(RB + 16777216);   // 8MB
  unsigned short* OB  = (unsigned short*)(RB + 25165824);   // 8MB
  unsigned short* H1B = (unsigned short*)(RB);              // 32MB FFN phase (= QB..OB)
  // attn bf16 partials in dead OWO region
  unsigned short* AP0 = (unsigned short*)(RB + 33554432);
  unsigned short* AP1 = (unsigned short*)(RB + 41943040);
  // o-proj split-K partials (QB/KB/VT free after attn; XB free after QKV)
  PtrQuad OPQ = { { QB, KB, VT, XB } };
  // FFN2 split-K partials (XB,X1B free; OWO region free)
  PtrQuad FPQ = { { XB, X1B, (unsigned short*)(RB + 33554432),
                    (unsigned short*)(RB + 41943040) } };
  PtrQuad ZQ = { { nullptr, nullptr, nullptr, nullptr } };

  const dim3 tb(256);
  cvt_bf16_kernel<<<dim3(4096), tb, 0, stream>>>(x, XB, 1048576);
  transpose_cvt<<<dim3(32, 32),  tb, 0, stream>>>(Wq, WQT, 1024, 1024);
  transpose_cvt<<<dim3(32, 32),  tb, 0, stream>>>(Wk, WKT, 1024, 1024);
  transpose_cvt<<<dim3(32, 32),  tb, 0, stream>>>(Wv, WVT, 1024, 1024);
  transpose_cvt<<<dim3(32, 32),  tb, 0, stream>>>(Wo, WOT, 1024, 1024);
  transpose_cvt<<<dim3(128, 32), tb, 0, stream>>>(W1, W1T, 1024, 4096);
  transpose_cvt<<<dim3(32, 128), tb, 0, stream>>>(W2, W2T, 4096, 1024);
  // QKV (N=3072): epilogue scatters Q(scaled), K, V(per-head transposed)
  gemm_bt<EPI_QKV><<<dim3(24, 32), tb, 0, stream>>>(XB, WQT, bq, bk, bv, (void*)QB, ZQ,
                                                    4096, 3072, 1024, 1024);
  // attention: 512 blocks x 512 thr, XCD-pinned (nb,sp) combos, sp=2, bf16 partials
  attn_kernel<<<dim3(512), dim3(512), 0, stream>>>(QB, KB, VT, AP0, AP1);
  reduce_o2<<<dim3(4096), tb, 0, stream>>>(AP0, AP1, OB, 1048576);
  // O-proj: split-K=4 (kLen 256) -> bf16 partials; reduce+bias+residual fused in LN1
  gemm_bt<EPI_PART><<<dim3(8, 32, 4), tb, 0, stream>>>(OB, WOT, nullptr, nullptr, nullptr,
                                                       nullptr, OPQ, 4096, 1024, 256, 1024);
  ln_red<<<dim3(4096), tb, 0, stream>>>(QB, KB, VT, XB, bo, x, g1, b1, X1, X1B);
  // FFN1 + exact GELU -> bf16
  gemm_bt<EPI_GELU><<<dim3(32, 32), tb, 0, stream>>>(X1B, W1T, c1, nullptr, nullptr,
                                                     (void*)H1B, ZQ, 4096, 4096, 1024, 1024);
  // FFN2: split-K=4 (kLen 1024) -> bf16 partials; reduce+bias+residual fused in LN2
  gemm_bt<EPI_PART><<<dim3(8, 32, 4), tb, 0, stream>>>(H1B, W2T, nullptr, nullptr, nullptr,
                                                       nullptr, FPQ, 4096, 1024, 1024, 4096);
  ln_red<<<dim3(4096), tb, 0, stream>>>(FPQ.p[0], FPQ.p[1], FPQ.p[2], FPQ.p[3], c2, X1,
                                        g2, b2, out, (unsigned short*)nullptr);
}

// Round 6
// 466.352 us; speedup vs baseline: 1.1231x; 1.0047x over previous
//
#include <hip/hip_runtime.h>
#include <cstdint>
#include <cstddef>

#define EPI_QKV  0
#define EPI_F32  2
#define EPI_GELU 3
#define EPI_PART 4

typedef __attribute__((ext_vector_type(8))) short bfrag8;   // 8 bf16 (4 VGPRs)
typedef __attribute__((ext_vector_type(4))) float facc4;    // 4 fp32 acc

struct PtrQuad { unsigned short* p[4]; };

__device__ __forceinline__ unsigned short f2b(float x) {
  unsigned int u = __builtin_bit_cast(unsigned int, x);
  u += 0x7FFFu + ((u >> 16) & 1u);   // RNE
  return (unsigned short)(u >> 16);
}
__device__ __forceinline__ float b2f(unsigned short u) {
  unsigned int x = ((unsigned int)u) << 16;
  return __builtin_bit_cast(float, x);
}

__device__ __forceinline__ void gl2lds16(const unsigned short* g, unsigned short* l) {
  __builtin_amdgcn_global_load_lds(
      (const __attribute__((address_space(1))) unsigned int*)g,
      (__attribute__((address_space(3))) unsigned int*)l, 16, 0, 0);
}

// ---------------- elementwise fp32 -> bf16 ----------------
__global__ __launch_bounds__(256)
void cvt_bf16_kernel(const float* __restrict__ in, unsigned short* __restrict__ out, int n4) {
  const int i = blockIdx.x * 256 + threadIdx.x;
  if (i < n4) {
    const float4 v = ((const float4*)in)[i];
    ushort4 u;
    u.x = f2b(v.x); u.y = f2b(v.y); u.z = f2b(v.z); u.w = f2b(v.w);
    ((ushort4*)out)[i] = u;
  }
}

// ---------------- transpose + convert: in (K x N) fp32 -> out (N x K) bf16 ----------------
__global__ __launch_bounds__(256)
void transpose_cvt(const float* __restrict__ in, unsigned short* __restrict__ out,
                   int K, int N) {
  __shared__ float tile[32][33];
  const int n0 = blockIdx.x * 32;
  const int k0 = blockIdx.y * 32;
  const int tx = threadIdx.x & 31, ty = threadIdx.x >> 5;  // ty 0..7
#pragma unroll
  for (int i = 0; i < 32; i += 8)
    tile[ty + i][tx] = in[(size_t)(k0 + ty + i) * N + n0 + tx];
  __syncthreads();
#pragma unroll
  for (int i = 0; i < 32; i += 8)
    out[(size_t)(n0 + ty + i) * K + k0 + tx] = f2b(tile[tx][ty + i]);
}

// ---------------- GEMM: C = A(MxK') @ Bt(NxK')^T slice, bf16 MFMA, fused epilogues ------
// 128x128 tile, BK=32, 4 waves (2x2), 4x4 16x16x32 MFMA per wave. m97 structure.
template<int EPI>
__global__ __launch_bounds__(256, 2)
void gemm_bt(const unsigned short* __restrict__ A,
             const unsigned short* __restrict__ Bt,
             const float* __restrict__ bias,
             const float* __restrict__ bias2,
             const float* __restrict__ bias3,
             void* __restrict__ out, PtrQuad pq,
             int M, int N, int K, int ldk) {
  __shared__ unsigned short sA[128 * 32];
  __shared__ unsigned short sB[128 * 32];
  const int tid  = threadIdx.x;
  const int lane = tid & 63;
  const int wave = tid >> 6;
  const int l15  = lane & 15, l4 = lane >> 4;
  const int wr = wave >> 1, wc = wave & 1;
  const long row0 = (long)blockIdx.y * 128;
  const long col0 = (long)blockIdx.x * 128;
  const long k0   = (long)blockIdx.z * K;

  facc4 acc[4][4];
#pragma unroll
  for (int i = 0; i < 4; i++)
#pragma unroll
    for (int j = 0; j < 4; j++) acc[i][j] = (facc4)0.f;

  const int srow = tid >> 2;
  const int scol = (tid & 3) * 8;
  const unsigned short* Ap0 = A  + (row0 + srow) * (long)ldk + k0 + scol;
  const unsigned short* Ap1 = Ap0 + 64 * (long)ldk;
  const unsigned short* Bp0 = Bt + (col0 + srow) * (long)ldk + k0 + scol;
  const unsigned short* Bp1 = Bp0 + 64 * (long)ldk;
  const int wbase = (tid & ~63) * 8;
  unsigned short* sA0 = &sA[wbase];
  unsigned short* sA1 = &sA[2048 + wbase];
  unsigned short* sB0 = &sB[wbase];
  unsigned short* sB1 = &sB[2048 + wbase];

  const int aoff = (wr * 64 + l15) * 32 + l4 * 8;
  const int boff = (wc * 64 + l15) * 32 + l4 * 8;

  for (int kt = 0; kt < K; kt += 32) {
    gl2lds16(Ap0 + kt, sA0);
    gl2lds16(Ap1 + kt, sA1);
    gl2lds16(Bp0 + kt, sB0);
    gl2lds16(Bp1 + kt, sB1);
    __syncthreads();
    bfrag8 af[4], bf[4];
#pragma unroll
    for (int i = 0; i < 4; i++) af[i] = *(const bfrag8*)&sA[aoff + i * 512];
#pragma unroll
    for (int j = 0; j < 4; j++) bf[j] = *(const bfrag8*)&sB[boff + j * 512];
#pragma unroll
    for (int i = 0; i < 4; i++)
#pragma unroll
      for (int j = 0; j < 4; j++)
        acc[i][j] = __builtin_amdgcn_mfma_f32_16x16x32_bf16(af[i], bf[j], acc[i][j], 0, 0, 0);
    __syncthreads();
  }

#pragma unroll
  for (int i = 0; i < 4; i++) {
    const long m0 = row0 + wr * 64 + i * 16 + l4 * 4;
#pragma unroll
    for (int j = 0; j < 4; j++) {
      const long c = col0 + wc * 64 + j * 16 + l15;
      if constexpr (EPI == EPI_QKV) {
        const long which = c >> 10;
        const long cl = c & 1023;
        unsigned short* oq = (unsigned short*)out;
        if (which == 0) {
          const float bj = bias[cl];
#pragma unroll
          for (int r = 0; r < 4; r++)
            oq[(m0 + r) * 1024 + cl] = f2b((acc[i][j][r] + bj) * 0.03125f);
        } else if (which == 1) {
          const float bj = bias2[cl];
#pragma unroll
          for (int r = 0; r < 4; r++)
            (oq + 4194304)[(m0 + r) * 1024 + cl] = f2b(acc[i][j][r] + bj);
        } else {
          const float bj = bias3[cl];
          const long cc = cl >> 6, d = cl & 63;
#pragma unroll
          for (int r = 0; r < 4; r++) {
            const long m = m0 + r;
            const long nbb = m >> 10, rr = m & 1023;
            const long h = rr >> 6, rhi = rr & 63;
            const long s = rhi * 16 + cc;
            (oq + 8388608)[((nbb * 16 + h) * 64 + d) * 1024 + s] = f2b(acc[i][j][r] + bj);
          }
        }
      } else if constexpr (EPI == EPI_F32) {
        const float bj = bias[c];
        float* of = (float*)out;
#pragma unroll
        for (int r = 0; r < 4; r++) of[(m0 + r) * (long)N + c] = acc[i][j][r] + bj;
      } else if constexpr (EPI == EPI_PART) {
        unsigned short* ob = pq.p[blockIdx.z];
#pragma unroll
        for (int r = 0; r < 4; r++) ob[(m0 + r) * (long)N + c] = f2b(acc[i][j][r]);
      } else {  // EPI_GELU -> bf16
        const float bj = bias[c];
        unsigned short* ob = (unsigned short*)out;
#pragma unroll
        for (int r = 0; r < 4; r++) {
          const float t = acc[i][j][r] + bj;
          ob[(m0 + r) * (long)N + c] = f2b(0.5f * t * (1.f + erff(t * 0.70710678f)));
        }
      }
    }
  }
}

// ---------------- fused attention v6 (softmax over HEADS at each (t,s)) ----------------
// 1D grid 512: id = tile*8 + combo, combo = nb + 4*sp (XCD-pinned slices, verified R5:
// FETCH 16 MB). 512 thr = 8 waves x 2 heads; t-tile 16; s-chunks 32 (16 iters).
// red[pb][wave][o] with o-stride 36: bank = l15 + 16*(l4&1) + c -> 2-way = free (R2-verified).
// abuf single-buffered wave-private (heads sequential). LDS 46 KB -> 3 blocks/CU.
__global__ __launch_bounds__(512, 4)
void attn_kernel(const unsigned short* __restrict__ Qb,
                 const unsigned short* __restrict__ Kb,
                 const unsigned short* __restrict__ Vt,
                 unsigned short* __restrict__ P0, unsigned short* __restrict__ P1) {
  const int id = blockIdx.x;
  const int combo = id & 7;
  const int tile = id >> 3;
  const int nb = combo & 3;
  const int sp = combo >> 2;
  const int tid = threadIdx.x, lane = tid & 63;
  const int w = __builtin_amdgcn_readfirstlane(tid >> 6);   // wave id 0..7 in SGPR
  const int l15 = lane & 15, l4 = lane >> 4;
  const int t0 = tile * 16;

  __shared__ float red[2][8][576];                          // 36 KB, dbuf, 2-way banks
  __shared__ __align__(16) unsigned short abuf[8][16][40];  // 10 KB, wave-private, shared by heads

  const size_t hb0 = (size_t)(nb * 16 + w * 2) << 16;
  const unsigned short* qB = Qb + hb0;
  const unsigned short* kB = Kb + hb0;
  const unsigned short* vB = Vt + hb0;

  // persistent Q A-frags (16 VGPRs)
  bfrag8 qf[2][2];
#pragma unroll
  for (int hh = 0; hh < 2; hh++)
#pragma unroll
    for (int ks = 0; ks < 2; ks++)
      qf[hh][ks] = *(const bfrag8*)(qB + (hh << 16) + (t0 + l15) * 64 + ks * 32 + l4 * 8);

  facc4 oacc[2][4];
#pragma unroll
  for (int hh = 0; hh < 2; hh++)
#pragma unroll
    for (int nt = 0; nt < 4; nt++) oacc[hh][nt] = (facc4)0.f;

  for (int it = 0; it < 16; ++it) {
    const int s0 = sp * 512 + it * 32;
    const int pb = it & 1;
    // ---- QK^T scores, 2 heads, 16t x 32s ----
    facc4 sacc[2][2];
#pragma unroll
    for (int hh = 0; hh < 2; hh++)
#pragma unroll
      for (int nt = 0; nt < 2; nt++) sacc[hh][nt] = (facc4)0.f;
#pragma unroll
    for (int hh = 0; hh < 2; hh++) {
      const unsigned short* kh = kB + (hh << 16);
#pragma unroll
      for (int ks = 0; ks < 2; ks++)
#pragma unroll
        for (int nt = 0; nt < 2; nt++) {
          const bfrag8 kf = *(const bfrag8*)(kh + (s0 + nt * 16 + l15) * 64 + ks * 32 + l4 * 8);
          sacc[hh][nt] = __builtin_amdgcn_mfma_f32_16x16x32_bf16(qf[hh][ks], kf, sacc[hh][nt], 0, 0, 0);
        }
    }
    // ---- prefetch both heads' V frags (latency hidden behind exp + barrier) ----
    bfrag8 vf0[4], vf1[4];
#pragma unroll
    for (int nt = 0; nt < 4; nt++) {
      vf0[nt] = *(const bfrag8*)(vB + (size_t)(nt * 16 + l15) * 1024 + s0 + l4 * 8);
      vf1[nt] = *(const bfrag8*)(vB + (1 << 16) + (size_t)(nt * 16 + l15) * 1024 + s0 + l4 * 8);
    }
    // ---- exp + 2-head partial sums -> red[pb][w][o] (2-way banks) ----
#pragma unroll
    for (int nt = 0; nt < 2; nt++)
#pragma unroll
      for (int r = 0; r < 4; r++) {
        const float e0 = __expf(sacc[0][nt][r]);
        const float e1 = __expf(sacc[1][nt][r]);
        sacc[0][nt][r] = e0; sacc[1][nt][r] = e1;
        red[pb][w][(l4 * 4 + r) * 36 + nt * 16 + l15] = e0 + e1;
      }
    __syncthreads();
    // ---- 16-head sum (8 scalar 2-way reads), reciprocal ----
    float rinv[2][4];
#pragma unroll
    for (int nt = 0; nt < 2; nt++)
#pragma unroll
      for (int r = 0; r < 4; r++) {
        const int o = (l4 * 4 + r) * 36 + nt * 16 + l15;
        float s = 0.f;
#pragma unroll
        for (int ww = 0; ww < 8; ww++) s += red[pb][ww][o];
        rinv[nt][r] = 1.f / s;
      }
    // ---- head 0: normalize -> abuf -> A-frag -> PV MFMA ----
#pragma unroll
    for (int nt = 0; nt < 2; nt++)
#pragma unroll
      for (int r = 0; r < 4; r++)
        abuf[w][l4 * 4 + r][nt * 16 + l15] = f2b(sacc[0][nt][r] * rinv[nt][r]);
    {
      const bfrag8 af0 = *(const bfrag8*)&abuf[w][l15][l4 * 8];
#pragma unroll
      for (int nt = 0; nt < 4; nt++)
        oacc[0][nt] = __builtin_amdgcn_mfma_f32_16x16x32_bf16(af0, vf0[nt], oacc[0][nt], 0, 0, 0);
    }
    // ---- head 1: same buffer (wave-private, program-order safe) ----
#pragma unroll
    for (int nt = 0; nt < 2; nt++)
#pragma unroll
      for (int r = 0; r < 4; r++)
        abuf[w][l4 * 4 + r][nt * 16 + l15] = f2b(sacc[1][nt][r] * rinv[nt][r]);
    {
      const bfrag8 af1 = *(const bfrag8*)&abuf[w][l15][l4 * 8];
#pragma unroll
      for (int nt = 0; nt < 4; nt++)
        oacc[1][nt] = __builtin_amdgcn_mfma_f32_16x16x32_bf16(af1, vf1[nt], oacc[1][nt], 0, 0, 0);
    }
  }
  // ---- bf16 partial O through the inverse view ----
  unsigned short* P = sp ? P1 : P0;
#pragma unroll
  for (int hh = 0; hh < 2; hh++) {
    const size_t rb = ((size_t)nb * 1024 + (size_t)(w * 2 + hh) * 64 + tile) * 1024;
#pragma unroll
    for (int nt = 0; nt < 4; nt++)
#pragma unroll
      for (int r = 0; r < 4; r++)
        P[rb + (size_t)(l4 * 4 + r) * 64 + nt * 16 + l15] = f2b(oacc[hh][nt][r]);
  }
}

// ---------------- reduce 2 bf16 partials -> bf16 ----------------
__global__ __launch_bounds__(256)
void reduce_o2(const unsigned short* __restrict__ P0, const unsigned short* __restrict__ P1,
               unsigned short* __restrict__ OB, int n4) {
  const int i = blockIdx.x * 256 + threadIdx.x;
  if (i < n4) {
    const ushort4 a = ((const ushort4*)P0)[i];
    const ushort4 b = ((const ushort4*)P1)[i];
    ushort4 u;
    u.x = f2b(b2f(a.x) + b2f(b.x));
    u.y = f2b(b2f(a.y) + b2f(b.y));
    u.z = f2b(b2f(a.z) + b2f(b.z));
    u.w = f2b(b2f(a.w) + b2f(b.w));
    ((ushort4*)OB)[i] = u;
  }
}

// ---- LayerNorm reducing 4 bf16 GEMM partials + bias + residual: out = LN(sum+b+res) ----
__global__ __launch_bounds__(256)
void ln_red(const unsigned short* __restrict__ P0, const unsigned short* __restrict__ P1,
            const unsigned short* __restrict__ P2, const unsigned short* __restrict__ P3,
            const float* __restrict__ bias, const float* __restrict__ resid,
            const float* __restrict__ g, const float* __restrict__ be,
            float* __restrict__ outf, unsigned short* __restrict__ outb) {
  const int row = blockIdx.x, tid = threadIdx.x;
  const size_t o4 = (size_t)row * 256 + tid;
  const ushort4 a = ((const ushort4*)P0)[o4];
  const ushort4 b = ((const ushort4*)P1)[o4];
  const ushort4 c = ((const ushort4*)P2)[o4];
  const ushort4 d = ((const ushort4*)P3)[o4];
  const float4 vb = ((const float4*)bias)[tid];
  const float4 vr = ((const float4*)resid)[o4];
  float t0 = b2f(a.x) + b2f(b.x) + b2f(c.x) + b2f(d.x) + vb.x + vr.x;
  float t1 = b2f(a.y) + b2f(b.y) + b2f(c.y) + b2f(d.y) + vb.y + vr.y;
  float t2 = b2f(a.z) + b2f(b.z) + b2f(c.z) + b2f(d.z) + vb.z + vr.z;
  float t3 = b2f(a.w) + b2f(b.w) + b2f(c.w) + b2f(d.w) + vb.w + vr.w;
  float s = t0 + t1 + t2 + t3;
  float q = t0 * t0 + t1 * t1 + t2 * t2 + t3 * t3;
#pragma unroll
  for (int off = 32; off > 0; off >>= 1) {
    s += __shfl_down(s, off, 64);
    q += __shfl_down(q, off, 64);
  }
  __shared__ float rs_[4], rq_[4];
  if ((tid & 63) == 0) { rs_[tid >> 6] = s; rq_[tid >> 6] = q; }
  __syncthreads();
  const float S = rs_[0] + rs_[1] + rs_[2] + rs_[3];
  const float Q = rq_[0] + rq_[1] + rq_[2] + rq_[3];
  const float mean = S * (1.f / 1024.f);
  const float var  = Q * (1.f / 1024.f) - mean * mean;
  const float rstd = rsqrtf(var + 1e-5f);
  const float4 vg  = ((const float4*)g)[tid];
  const float4 vbe = ((const float4*)be)[tid];
  float o0 = (t0 - mean) * rstd * vg.x + vbe.x;
  float o1 = (t1 - mean) * rstd * vg.y + vbe.y;
  float o2 = (t2 - mean) * rstd * vg.z + vbe.z;
  float o3 = (t3 - mean) * rstd * vg.w + vbe.w;
  ((float4*)(outf + (size_t)row * 1024))[tid] = make_float4(o0, o1, o2, o3);
  if (outb != nullptr) {
    ushort4 u;
    u.x = f2b(o0); u.y = f2b(o1); u.z = f2b(o2); u.w = f2b(o3);
    ((ushort4*)(outb + (size_t)row * 1024))[tid] = u;
  }
}

// ---------------- launch ----------------
extern "C" void kernel_launch(void* const* d_in, const int* in_sizes, int n_in,
                              void* d_out, int out_size, void* d_ws, size_t ws_size,
                              hipStream_t stream) {
  const float* x  = (const float*)d_in[0];
  const float* Wq = (const float*)d_in[1];
  const float* bq = (const float*)d_in[2];
  const float* Wk = (const float*)d_in[3];
  const float* bk = (const float*)d_in[4];
  const float* Wv = (const float*)d_in[5];
  const float* bv = (const float*)d_in[6];
  const float* Wo = (const float*)d_in[7];
  const float* bo = (const float*)d_in[8];
  const float* g1 = (const float*)d_in[9];
  const float* b1 = (const float*)d_in[10];
  const float* W1 = (const float*)d_in[11];
  const float* c1 = (const float*)d_in[12];
  const float* W2 = (const float*)d_in[13];
  const float* c2 = (const float*)d_in[14];
  const float* g2 = (const float*)d_in[15];
  const float* b2 = (const float*)d_in[16];
  float* out = (float*)d_out;

  char* ws = (char*)d_ws;
  unsigned short* XB  = (unsigned short*)(ws);              // 8MB  x bf16
  unsigned short* WQT = (unsigned short*)(ws + 8388608);    // 2MB
  unsigned short* WKT = (unsigned short*)(ws + 10485760);   // 2MB
  unsigned short* WVT = (unsigned short*)(ws + 12582912);   // 2MB
  unsigned short* WOT = (unsigned short*)(ws + 14680064);   // 2MB
  unsigned short* W1T = (unsigned short*)(ws + 16777216);   // 8MB
  unsigned short* W2T = (unsigned short*)(ws + 25165824);   // 8MB
  float*          X1  = (float*)(ws + 33554432);            // 16MB fp32 (LN1 out)
  unsigned short* X1B = (unsigned short*)(ws + 50331648);   // 8MB
  char* RB = ws + 58720256;                                 // 48MB union region
  unsigned short* QB  = (unsigned short*)(RB);              // 8MB
  unsigned short* KB  = (unsigned short*)(RB + 8388608);    // 8MB
  unsigned short* VT  = (unsigned short*)(RB + 16777216);   // 8MB
  unsigned short* OB  = (unsigned short*)(RB + 25165824);   // 8MB
  unsigned short* H1B = (unsigned short*)(RB);              // 32MB FFN phase (= QB..OB)
  // attn bf16 partials in dead OWO region
  unsigned short* AP0 = (unsigned short*)(RB + 33554432);
  unsigned short* AP1 = (unsigned short*)(RB + 41943040);
  // o-proj split-K partials (QB/KB/VT free after attn; XB free after QKV)
  PtrQuad OPQ = { { QB, KB, VT, XB } };
  // FFN2 split-K partials (XB,X1B free; OWO region free)
  PtrQuad FPQ = { { XB, X1B, (unsigned short*)(RB + 33554432),
                    (unsigned short*)(RB + 41943040) } };
  PtrQuad ZQ = { { nullptr, nullptr, nullptr, nullptr } };

  const dim3 tb(256);
  cvt_bf16_kernel<<<dim3(4096), tb, 0, stream>>>(x, XB, 1048576);
  transpose_cvt<<<dim3(32, 32),  tb, 0, stream>>>(Wq, WQT, 1024, 1024);
  transpose_cvt<<<dim3(32, 32),  tb, 0, stream>>>(Wk, WKT, 1024, 1024);
  transpose_cvt<<<dim3(32, 32),  tb, 0, stream>>>(Wv, WVT, 1024, 1024);
  transpose_cvt<<<dim3(32, 32),  tb, 0, stream>>>(Wo, WOT, 1024, 1024);
  transpose_cvt<<<dim3(128, 32), tb, 0, stream>>>(W1, W1T, 1024, 4096);
  transpose_cvt<<<dim3(32, 128), tb, 0, stream>>>(W2, W2T, 4096, 1024);
  // QKV (N=3072): epilogue scatters Q(scaled), K, V(per-head transposed)
  gemm_bt<EPI_QKV><<<dim3(24, 32), tb, 0, stream>>>(XB, WQT, bq, bk, bv, (void*)QB, ZQ,
                                                    4096, 3072, 1024, 1024);
  // attention: 512 blocks x 512 thr, XCD-pinned combos, sp=2, bf16 partials
  attn_kernel<<<dim3(512), dim3(512), 0, stream>>>(QB, KB, VT, AP0, AP1);
  reduce_o2<<<dim3(4096), tb, 0, stream>>>(AP0, AP1, OB, 1048576);
  // O-proj: split-K=4 (kLen 256) -> bf16 partials; reduce+bias+residual fused in LN1
  gemm_bt<EPI_PART><<<dim3(8, 32, 4), tb, 0, stream>>>(OB, WOT, nullptr, nullptr, nullptr,
                                                       nullptr, OPQ, 4096, 1024, 256, 1024);
  ln_red<<<dim3(4096), tb, 0, stream>>>(QB, KB, VT, XB, bo, x, g1, b1, X1, X1B);
  // FFN1 + exact GELU -> bf16
  gemm_bt<EPI_GELU><<<dim3(32, 32), tb, 0, stream>>>(X1B, W1T, c1, nullptr, nullptr,
                                                     (void*)H1B, ZQ, 4096, 4096, 1024, 1024);
  // FFN2: split-K=4 (kLen 1024) -> bf16 partials; reduce+bias+residual fused in LN2
  gemm_bt<EPI_PART><<<dim3(8, 32, 4), tb, 0, stream>>>(H1B, W2T, nullptr, nullptr, nullptr,
                                                       nullptr, FPQ, 4096, 1024, 1024, 4096);
  ln_red<<<dim3(4096), tb, 0, stream>>>(FPQ.p[0], FPQ.p[1], FPQ.p[2], FPQ.p[3], c2, X1,
                                        g2, b2, out, (unsigned short*)nullptr);
}